// Round 1
// baseline (1364.202 us; speedup 1.0000x reference)
//
#include <hip/hip_runtime.h>
#include <hip/hip_bf16.h>

// Problem constants (fixed by reference)
#define BB    4
#define NN    1024         // NQ == NK
#define DM    1024         // d_model
#define HH    16
#define DK    64
#define HID   512
#define TT    (BB * NN)    // 4096 tokens

// ---------------------------------------------------------------------------
// Mask-dtype detector.  attention_mask is jnp bool; the harness may push it as
// 1-byte bool, int32(0/1), or float32(0/1).  Scan first BB*NN*NN bytes (safe
// lower bound in all cases):
//   flags[0]=1 if any nonzero byte at pos%4!=0, flags[1]=1 if any at pos%4==0.
//   (1,1) -> bool bytes, (0,1) -> int32, (1,0) -> float32, (0,0) -> all-unmasked.
// ---------------------------------------------------------------------------
__global__ void detect_mask_kernel(const unsigned char* __restrict__ m,
                                   int nbytes, int* __restrict__ flags) {
    int stride = blockDim.x * gridDim.x;
    int hi = 0, lo = 0;
    for (int i = blockIdx.x * blockDim.x + threadIdx.x; i < nbytes; i += stride) {
        unsigned char v = m[i];
        if (v) { if (i & 3) hi = 1; else lo = 1; }
    }
    if (hi) atomicOr(&flags[0], 1);
    if (lo) atomicOr(&flags[1], 1);
}

// ---------------------------------------------------------------------------
// Tiled f32 GEMM:  C[m][n] = epilogue( sum_k A[m][k]*W[n][k] + bias[n] )
// A: (M,K) row-major; W: (N,K) row-major (torch Linear weight).
// Tile 128(M) x 64(N) x 16(K); 256 threads; 8x4 per thread.
// EP: 0 = bias, 1 = relu, 2 = gate (C = X * sigmoid(.)), 3 = mm-scale
//     (C = (.) * (mem[m]*Wmm[n] + bmm[n]))
// ---------------------------------------------------------------------------
template <int EP>
__global__ __launch_bounds__(256) void gemm_f32(
    const float* __restrict__ A, const float* __restrict__ W,
    const float* __restrict__ bias, float* __restrict__ C,
    int M, int N, int K,
    const float* __restrict__ X,
    const float* __restrict__ mem,
    const float* __restrict__ Wmm,
    const float* __restrict__ bmm)
{
    __shared__ float As[16][128];   // [k][m]
    __shared__ float Bs[16][64];    // [k][n]
    const int tid = threadIdx.x;
    const int m0 = blockIdx.x * 128, n0 = blockIdx.y * 64;
    const int tm = (tid >> 4) * 8, tn = (tid & 15) * 4;

    float acc[8][4] = {};

    for (int k0 = 0; k0 < K; k0 += 16) {
        // A tile: 128x16 floats = 512 float4, 2 per thread (transposed store)
        #pragma unroll
        for (int i = 0; i < 2; ++i) {
            int f = tid + i * 256;
            int m = f >> 2, kq = f & 3;
            float4 v = *(const float4*)&A[(size_t)(m0 + m) * K + k0 + kq * 4];
            As[kq * 4 + 0][m] = v.x; As[kq * 4 + 1][m] = v.y;
            As[kq * 4 + 2][m] = v.z; As[kq * 4 + 3][m] = v.w;
        }
        // W tile: 64x16 floats = 256 float4, 1 per thread
        {
            int n = tid >> 2, kq = tid & 3;
            float4 v = *(const float4*)&W[(size_t)(n0 + n) * K + k0 + kq * 4];
            Bs[kq * 4 + 0][n] = v.x; Bs[kq * 4 + 1][n] = v.y;
            Bs[kq * 4 + 2][n] = v.z; Bs[kq * 4 + 3][n] = v.w;
        }
        __syncthreads();
        #pragma unroll
        for (int k = 0; k < 16; ++k) {
            float a[8], b4[4];
            *(float4*)&a[0] = *(const float4*)&As[k][tm];
            *(float4*)&a[4] = *(const float4*)&As[k][tm + 4];
            *(float4*)&b4[0] = *(const float4*)&Bs[k][tn];
            #pragma unroll
            for (int i = 0; i < 8; ++i)
                #pragma unroll
                for (int j = 0; j < 4; ++j)
                    acc[i][j] += a[i] * b4[j];
        }
        __syncthreads();
    }

    // epilogue
    float4 bb4 = *(const float4*)&bias[n0 + tn];
    const float ba[4] = {bb4.x, bb4.y, bb4.z, bb4.w};
    float wmv[4] = {0, 0, 0, 0}, bmv[4] = {0, 0, 0, 0};
    if (EP == 3) {
        float4 w4 = *(const float4*)&Wmm[n0 + tn];
        float4 m4 = *(const float4*)&bmm[n0 + tn];
        wmv[0] = w4.x; wmv[1] = w4.y; wmv[2] = w4.z; wmv[3] = w4.w;
        bmv[0] = m4.x; bmv[1] = m4.y; bmv[2] = m4.z; bmv[3] = m4.w;
    }
    #pragma unroll
    for (int i = 0; i < 8; ++i) {
        int m = m0 + tm + i;
        size_t crow = (size_t)m * N + n0 + tn;
        float xv[4] = {0, 0, 0, 0};
        if (EP == 2) {
            float4 x4 = *(const float4*)&X[crow];
            xv[0] = x4.x; xv[1] = x4.y; xv[2] = x4.z; xv[3] = x4.w;
        }
        float mval = (EP == 3) ? mem[m] : 0.0f;
        float out[4];
        #pragma unroll
        for (int j = 0; j < 4; ++j) {
            float v = acc[i][j] + ba[j];
            if (EP == 1) v = fmaxf(v, 0.0f);
            if (EP == 2) v = xv[j] * (1.0f / (1.0f + __expf(-v)));
            if (EP == 3) v = v * (mval * wmv[j] + bmv[j]);
            out[j] = v;
        }
        *(float4*)&C[crow] = *(const float4*)out;
    }
}

// ---------------------------------------------------------------------------
// Fused attention (f32).  One block = one (b,h) x 64 q-rows.
// S = (Q/8) @ Ks^T; S *= aw; masked -> P=0 else P=exp(S) (max-free: logits are
// O(1e-2), no overflow possible); O = P @ Vs; out = O / rowsum(P).
// Layouts in LDS: Qs/Ks d-major [d][row] for float4 reads; Vs natural [c][d];
// Ps [r][c].  Ks and Vs time-share one buffer (4 barriers/tile) to fit 64 KB.
// ---------------------------------------------------------------------------
__global__ __launch_bounds__(256) void attn_fused(
    const float* __restrict__ qp, const float* __restrict__ ksb,
    const float* __restrict__ vsb, const float* __restrict__ aw,
    const void* __restrict__ maskp, const int* __restrict__ mflags,
    float* __restrict__ ob)
{
    __shared__ float Qs[64][68];   // [d][r], pre-scaled by 1/8
    __shared__ float KV[64][68];   // Ks as [d][c], then Vs as [c][d]
    __shared__ float Ps[64][68];   // [r][c]
    const int tid = threadIdx.x;
    const int tx = tid & 15, ty = tid >> 4;
    const int r0 = ty * 4, c0 = tx * 4;
    const int qt = blockIdx.x, bh = blockIdx.y;
    const int b = bh >> 4, h = bh & 15;
    const int q0 = qt * 64;
    const int fA = mflags[0], fB = mflags[1];
    const int mode = fA ? (fB ? 1 : 2) : 0;   // 1=bool byte, 2=float, 0=int32

    // load Q tile transposed + scaled
    #pragma unroll
    for (int i = 0; i < 4; ++i) {
        int f = tid + i * 256;           // float4 index 0..1023
        int r = f >> 4, dq = f & 15;
        float4 v = *(const float4*)&qp[((size_t)(b * NN + q0 + r)) * DM + h * 64 + dq * 4];
        Qs[dq * 4 + 0][r] = v.x * 0.125f; Qs[dq * 4 + 1][r] = v.y * 0.125f;
        Qs[dq * 4 + 2][r] = v.z * 0.125f; Qs[dq * 4 + 3][r] = v.w * 0.125f;
    }

    float o[4][4] = {};
    float lpart[4] = {0.f, 0.f, 0.f, 0.f};

    for (int kt = 0; kt < 16; ++kt) {
        const int k0 = kt * 64;
        // load K tile transposed [d][c]
        #pragma unroll
        for (int i = 0; i < 4; ++i) {
            int f = tid + i * 256;
            int c = f >> 4, dq = f & 15;
            float4 v = *(const float4*)&ksb[((size_t)(b * NN + k0 + c)) * DM + h * 64 + dq * 4];
            KV[dq * 4 + 0][c] = v.x; KV[dq * 4 + 1][c] = v.y;
            KV[dq * 4 + 2][c] = v.z; KV[dq * 4 + 3][c] = v.w;
        }
        __syncthreads();                         // bar1: Q(first iter)+K ready

        float s[4][4] = {};
        for (int d = 0; d < 64; ++d) {
            float a[4], bk4[4];
            *(float4*)a   = *(const float4*)&Qs[d][r0];
            *(float4*)bk4 = *(const float4*)&KV[d][c0];
            #pragma unroll
            for (int i = 0; i < 4; ++i)
                #pragma unroll
                for (int j = 0; j < 4; ++j)
                    s[i][j] += a[i] * bk4[j];
        }

        // aw * mask * exp -> Ps, accumulate row partial sums
        #pragma unroll
        for (int i = 0; i < 4; ++i) {
            int qrow = q0 + r0 + i;
            size_t awoff = (((size_t)(b * HH + h)) * NN + qrow) * NN + k0 + c0;
            size_t moff  = (((size_t)b) * NN + qrow) * NN + k0 + c0;
            float4 awv = *(const float4*)&aw[awoff];
            const float awa[4] = {awv.x, awv.y, awv.z, awv.w};
            float p[4];
            #pragma unroll
            for (int j = 0; j < 4; ++j) {
                float att = s[i][j] * awa[j];
                bool mk;
                if (mode == 1)      mk = ((const unsigned char*)maskp)[moff + j] != 0;
                else if (mode == 0) mk = ((const int*)maskp)[moff + j] != 0;
                else                mk = ((const float*)maskp)[moff + j] != 0.0f;
                float pv = mk ? 0.0f : __expf(att);
                p[j] = pv;
                lpart[i] += pv;
            }
            *(float4*)&Ps[r0 + i][c0] = *(const float4*)p;
        }
        __syncthreads();                         // bar2: K reads done, P visible

        // load V tile natural [c][d] into same buffer
        #pragma unroll
        for (int i = 0; i < 4; ++i) {
            int f = tid + i * 256;
            int c = f >> 4, dq = f & 15;
            float4 v = *(const float4*)&vsb[((size_t)(b * NN + k0 + c)) * DM + h * 64 + dq * 4];
            *(float4*)&KV[c][dq * 4] = v;
        }
        __syncthreads();                         // bar3: V ready

        for (int c = 0; c < 64; ++c) {
            float pr[4], vv[4];
            #pragma unroll
            for (int i = 0; i < 4; ++i) pr[i] = Ps[r0 + i][c];
            *(float4*)vv = *(const float4*)&KV[c][c0];
            #pragma unroll
            for (int i = 0; i < 4; ++i)
                #pragma unroll
                for (int j = 0; j < 4; ++j)
                    o[i][j] += pr[i] * vv[j];
        }
        __syncthreads();                         // bar4: V/P reads done
    }

    // normalize and write (b, q, h*64+d) rows
    #pragma unroll
    for (int i = 0; i < 4; ++i) {
        float l = lpart[i];
        #pragma unroll
        for (int off = 1; off < 16; off <<= 1) l += __shfl_xor(l, off);
        float inv = 1.0f / l;
        float4 r = make_float4(o[i][0] * inv, o[i][1] * inv, o[i][2] * inv, o[i][3] * inv);
        *(float4*)&ob[((size_t)(b * NN + q0 + r0 + i)) * DM + h * 64 + c0] = r;
    }
}

// ---------------------------------------------------------------------------
extern "C" void kernel_launch(void* const* d_in, const int* in_sizes, int n_in,
                              void* d_out, int out_size, void* d_ws, size_t ws_size,
                              hipStream_t stream) {
    const float* queries = (const float*)d_in[0];
    const float* keys    = (const float*)d_in[1];
    const float* values  = (const float*)d_in[2];
    const void*  maskp   = d_in[3];
    const float* aw      = (const float*)d_in[4];
    const float* memv    = (const float*)d_in[5];
    const float* Wq  = (const float*)d_in[6];   const float* bq  = (const float*)d_in[7];
    const float* Wk  = (const float*)d_in[8];   const float* bk  = (const float*)d_in[9];
    const float* Wv  = (const float*)d_in[10];  const float* bv  = (const float*)d_in[11];
    const float* Wo  = (const float*)d_in[12];  const float* bo  = (const float*)d_in[13];
    const float* Wmm = (const float*)d_in[14];  const float* bmm = (const float*)d_in[15];
    const float* W1a[3] = {(const float*)d_in[16], (const float*)d_in[20], (const float*)d_in[24]};
    const float* b1a[3] = {(const float*)d_in[17], (const float*)d_in[21], (const float*)d_in[25]};
    const float* W2a[3] = {(const float*)d_in[18], (const float*)d_in[22], (const float*)d_in[26]};
    const float* b2a[3] = {(const float*)d_in[19], (const float*)d_in[23], (const float*)d_in[27]};

    char* ws = (char*)d_ws;
    const size_t SZ_H  = (size_t)TT * HID * 4;   // 8 MiB
    const size_t SZ_TD = (size_t)TT * DM * 4;    // 16 MiB
    int*   mflags = (int*)ws;
    float* hbuf = (float*)(ws + 256);
    float* xg   = (float*)(ws + 256 + SZ_H);
    float* qp   = (float*)(ws + 256 + SZ_H + SZ_TD);
    float* ksb  = (float*)(ws + 256 + SZ_H + 2 * SZ_TD);
    float* vsb  = (float*)(ws + 256 + SZ_H + 3 * SZ_TD);
    float* obuf = (float*)(ws + 256 + SZ_H + 4 * SZ_TD);

    hipMemsetAsync(mflags, 0, 8, stream);
    detect_mask_kernel<<<512, 256, 0, stream>>>((const unsigned char*)maskp,
                                                BB * NN * NN, mflags);

    const dim3 blk(256);
    const dim3 g_fc1(TT / 128, HID / 64);   // (32, 8)
    const dim3 g_big(TT / 128, DM / 64);    // (32, 16)

    const float* xin[3]  = {queries, keys, values};
    const float* Wp[3]   = {Wq, Wk, Wv};
    const float* bp[3]   = {bq, bk, bv};
    float*       dst[3]  = {qp, ksb, vsb};

    for (int t = 0; t < 3; ++t) {
        gemm_f32<1><<<g_fc1, blk, 0, stream>>>(xin[t], W1a[t], b1a[t], hbuf,
                                               TT, HID, DM, nullptr, nullptr, nullptr, nullptr);
        gemm_f32<2><<<g_big, blk, 0, stream>>>(hbuf, W2a[t], b2a[t], xg,
                                               TT, DM, HID, xin[t], nullptr, nullptr, nullptr);
        if (t == 0) {
            gemm_f32<0><<<g_big, blk, 0, stream>>>(xg, Wp[t], bp[t], dst[t],
                                                   TT, DM, DM, nullptr, nullptr, nullptr, nullptr);
        } else {
            gemm_f32<3><<<g_big, blk, 0, stream>>>(xg, Wp[t], bp[t], dst[t],
                                                   TT, DM, DM, nullptr, memv, Wmm, bmm);
        }
    }

    attn_fused<<<dim3(NN / 64, BB * HH), blk, 0, stream>>>(qp, ksb, vsb, aw,
                                                           maskp, mflags, obuf);

    gemm_f32<0><<<g_big, blk, 0, stream>>>(obuf, Wo, bo, (float*)d_out,
                                           TT, DM, DM, nullptr, nullptr, nullptr, nullptr);
}

// Round 2
// 389.363 us; speedup vs baseline: 3.5037x; 3.5037x over previous
//
#include <hip/hip_runtime.h>
#include <hip/hip_bf16.h>

#define BB    4
#define NN    1024
#define DM    1024
#define HH    16
#define HID   512
#define TT    (BB * NN)

typedef __attribute__((ext_vector_type(8))) short bf16x8;
typedef __attribute__((ext_vector_type(4))) float f32x4;

__device__ __forceinline__ ushort f2bfu(float f) {
    __hip_bfloat16 h = __float2bfloat16(f);
    return __builtin_bit_cast(ushort, h);
}

__device__ __forceinline__ f32x4 mfma16(bf16x8 a, bf16x8 b, f32x4 c) {
    return __builtin_amdgcn_mfma_f32_16x16x32_bf16(a, b, c, 0, 0, 0);
}

// async 16B/lane global->LDS; lds dest = wave-uniform base + lane*16
__device__ __forceinline__ void gll16(const void* g, void* l) {
    __builtin_amdgcn_global_load_lds(
        (const __attribute__((address_space(1))) unsigned int*)g,
        (__attribute__((address_space(3))) unsigned int*)l, 16, 0, 0);
}

// ---------------------------------------------------------------------------
__global__ void detect_mask_kernel(const unsigned char* __restrict__ m,
                                   int nbytes, int* __restrict__ flags) {
    int stride = blockDim.x * gridDim.x;
    int hi = 0, lo = 0;
    for (int i = blockIdx.x * blockDim.x + threadIdx.x; i < nbytes; i += stride) {
        unsigned char v = m[i];
        if (v) { if (i & 3) hi = 1; else lo = 1; }
    }
    if (hi) atomicOr(&flags[0], 1);
    if (lo) atomicOr(&flags[1], 1);
}

// ---------------------------------------------------------------------------
__global__ void cvt_bf16(const float* __restrict__ src, ushort* __restrict__ dst, int n4) {
    int stride = blockDim.x * gridDim.x;
    for (int i = blockIdx.x * blockDim.x + threadIdx.x; i < n4; i += stride) {
        float4 v = ((const float4*)src)[i];
        uint2 o;
        o.x = (unsigned)f2bfu(v.x) | ((unsigned)f2bfu(v.y) << 16);
        o.y = (unsigned)f2bfu(v.z) | ((unsigned)f2bfu(v.w) << 16);
        ((uint2*)dst)[i] = o;
    }
}

// ---------------------------------------------------------------------------
// bf16 MFMA GEMM: C[m][e] = epi( sum_k A[m][k] * W[e][k] + bias[e] )
// BM=BN=128, BK=64, 256 thr (4 waves, each 64x64 = 4x4 frags of 16x16x32).
// LDS tiles [128 rows][64 bf16] with 16B-slot XOR swizzle (row&7)<<4 bytes,
// applied on the pre-swizzled global source (global_load_lds writes linear).
// EP: 0 bias*scale->bf16 | 1 relu->bf16 | 2 X*sigmoid->bf16 |
//     3 (.)*(mem*Wmm+bmm)->bf16 | 4 bias->f32 | 5 EP3 + transposed store to
//     vt[b][h][d][n] (packed 4 consecutive n per 8B store)
// ---------------------------------------------------------------------------
template <int EP>
__global__ __launch_bounds__(256) void gemm_bf16(
    const ushort* __restrict__ A, const ushort* __restrict__ W,
    const float* __restrict__ bias, void* __restrict__ Cout,
    int M, int N, int K, float scale,
    const float* __restrict__ X,
    const float* __restrict__ mem, const float* __restrict__ Wmm,
    const float* __restrict__ bmm)
{
    __shared__ __align__(16) ushort As[128 * 64];
    __shared__ __align__(16) ushort Bs[128 * 64];
    const int tid = threadIdx.x;
    const int lane = tid & 63, w = tid >> 6;
    const int lc = lane & 15, lg = lane >> 4;
    const int m0 = blockIdx.x * 128, n0 = blockIdx.y * 128;
    const int wm = (w >> 1) * 64, wn = (w & 1) * 64;
    const int srow = lane >> 3, scol = 8 * ((lane & 7) ^ srow);
    const int swl = (lc & 7) << 3;   // element-unit swizzle for frag reads

    f32x4 acc[4][4];
    #pragma unroll
    for (int i = 0; i < 4; ++i)
        #pragma unroll
        for (int j = 0; j < 4; ++j)
            acc[i][j] = (f32x4){0.f, 0.f, 0.f, 0.f};

    // prologue stage k0=0: 16 chunks (8 rows x 64 elems = 1024B) per tile
    #pragma unroll
    for (int ci = 0; ci < 4; ++ci) {
        int c = w + ci * 4;
        gll16(&A[(size_t)(m0 + c * 8 + srow) * K + 0 + scol], &As[c * 512]);
        gll16(&W[(size_t)(n0 + c * 8 + srow) * K + 0 + scol], &Bs[c * 512]);
    }

    for (int k0 = 0; k0 < K; k0 += 64) {
        __syncthreads();   // staged tile ready (compiler drains vmcnt)
        bf16x8 af[4][2], bfr[4][2];
        #pragma unroll
        for (int mi = 0; mi < 4; ++mi) {
            int row = wm + mi * 16 + lc;
            af[mi][0] = *(const bf16x8*)&As[row * 64 + ((lg * 8) ^ swl)];
            af[mi][1] = *(const bf16x8*)&As[row * 64 + ((32 + lg * 8) ^ swl)];
        }
        #pragma unroll
        for (int nj = 0; nj < 4; ++nj) {
            int row = wn + nj * 16 + lc;
            bfr[nj][0] = *(const bf16x8*)&Bs[row * 64 + ((lg * 8) ^ swl)];
            bfr[nj][1] = *(const bf16x8*)&Bs[row * 64 + ((32 + lg * 8) ^ swl)];
        }
        #pragma unroll
        for (int mi = 0; mi < 4; ++mi)
            #pragma unroll
            for (int nj = 0; nj < 4; ++nj) {
                acc[mi][nj] = mfma16(af[mi][0], bfr[nj][0], acc[mi][nj]);
                acc[mi][nj] = mfma16(af[mi][1], bfr[nj][1], acc[mi][nj]);
            }
        __syncthreads();   // all frag reads done
        if (k0 + 64 < K) {
            int kn = k0 + 64;
            #pragma unroll
            for (int ci = 0; ci < 4; ++ci) {
                int c = w + ci * 4;
                gll16(&A[(size_t)(m0 + c * 8 + srow) * K + kn + scol], &As[c * 512]);
                gll16(&W[(size_t)(n0 + c * 8 + srow) * K + kn + scol], &Bs[c * 512]);
            }
        }
    }

    // epilogue: C row = m0+wm+mi*16+lg*4+r, col = n0+wn+nj*16+lc
    #pragma unroll
    for (int nj = 0; nj < 4; ++nj) {
        int e = n0 + wn + nj * 16 + lc;
        float bv = bias[e];
        float wmv = 0.f, bmv = 0.f;
        if (EP == 3 || EP == 5) { wmv = Wmm[e]; bmv = bmm[e]; }
        #pragma unroll
        for (int mi = 0; mi < 4; ++mi) {
            int mbase = m0 + wm + mi * 16 + lg * 4;
            if (EP == 5) {
                ushort u[4];
                #pragma unroll
                for (int r = 0; r < 4; ++r) {
                    float v = (acc[mi][nj][r] + bv) * (mem[mbase + r] * wmv + bmv);
                    u[r] = f2bfu(v);
                }
                int bb = mbase >> 10, n = mbase & 1023;
                size_t off = ((size_t)(bb * HH + (e >> 6)) * 64 + (e & 63)) * NN + n;
                uint2 pk;
                pk.x = (unsigned)u[0] | ((unsigned)u[1] << 16);
                pk.y = (unsigned)u[2] | ((unsigned)u[3] << 16);
                *(uint2*)&((ushort*)Cout)[off] = pk;
            } else {
                #pragma unroll
                for (int r = 0; r < 4; ++r) {
                    int m = mbase + r;
                    float v = acc[mi][nj][r] + bv;
                    if (EP == 1) v = fmaxf(v, 0.f);
                    if (EP == 2) v = X[(size_t)m * N + e] * (1.f / (1.f + __expf(-v)));
                    if (EP == 3) v = v * (mem[m] * wmv + bmv);
                    if (EP == 0) v = v * scale;
                    size_t off = (size_t)m * N + e;
                    if (EP == 4) ((float*)Cout)[off] = v;
                    else         ((ushort*)Cout)[off] = f2bfu(v);
                }
            }
        }
    }
}

// ---------------------------------------------------------------------------
// MFMA flash attention. Block = (b,h, 64 q-rows), 4 waves, wave w owns q-cols
// wq..wq+16 of S^T = K·Q^T (A=K rows, B=Q rows, both LDS row-reads).
// Lane holds S^T[k=mi*16+lg*4+r][q=wq+lc]: 4 consecutive k per reg quad ->
// float4 aw/mask loads, scalar per-lane row-sum, one ds_write_b64 per frag
// for P (bf16). PV: A=P rows (q), B=Vt rows (d) -> out[q][d], f32 acc.
// Max-free softmax (logits ~1e-2): p = mask ? 0 : exp(s*aw); out /= sum(p).
// ---------------------------------------------------------------------------
__global__ __launch_bounds__(256) void attn_mfma(
    const ushort* __restrict__ qp, const ushort* __restrict__ kp,
    const ushort* __restrict__ vt, const float* __restrict__ aw,
    const void* __restrict__ maskp, const int* __restrict__ mflags,
    ushort* __restrict__ ob)
{
    __shared__ __align__(16) ushort Qs[64 * 64];
    __shared__ __align__(16) ushort Ks[64 * 64];
    __shared__ __align__(16) ushort Vs[64 * 64];
    __shared__ __align__(16) ushort Ps[64 * 64];
    const int tid = threadIdx.x, lane = tid & 63, w = tid >> 6;
    const int lc = lane & 15, lg = lane >> 4;
    const int qt = blockIdx.x, bh = blockIdx.y;
    const int b = bh >> 4, h = bh & 15;
    const int q0 = qt * 64, wq = w * 16;
    const int mode = mflags[0] ? (mflags[1] ? 1 : 2) : 0;
    const int srow = lane >> 3, scol = 8 * ((lane & 7) ^ srow);
    const int swl = (lc & 7) << 3;

    // stage Q (once) + K/V tile 0
    #pragma unroll
    for (int ci = 0; ci < 2; ++ci) {
        int c = w + ci * 4;
        gll16(&qp[(size_t)(b * NN + q0 + c * 8 + srow) * DM + h * 64 + scol], &Qs[c * 512]);
        gll16(&kp[(size_t)(b * NN + 0 + c * 8 + srow) * DM + h * 64 + scol], &Ks[c * 512]);
        gll16(&vt[(size_t)(bh * 64 + c * 8 + srow) * NN + 0 + scol], &Vs[c * 512]);
    }

    f32x4 oacc[4];
    #pragma unroll
    for (int i = 0; i < 4; ++i) oacc[i] = (f32x4){0.f, 0.f, 0.f, 0.f};
    float psum = 0.f;
    const int q = q0 + wq + lc;                      // this lane's q row (S^T)
    const float* awrow = aw + ((size_t)(bh) * NN + q) * NN;
    const size_t mrowo = ((size_t)b * NN + q) * NN;

    for (int t = 0; t < 16; ++t) {
        const int k0 = t * 64;
        __syncthreads();   // staged K/V ready

        bf16x8 bq0 = *(const bf16x8*)&Qs[(wq + lc) * 64 + ((lg * 8) ^ swl)];
        bf16x8 bq1 = *(const bf16x8*)&Qs[(wq + lc) * 64 + ((32 + lg * 8) ^ swl)];
        f32x4 sacc[4];
        #pragma unroll
        for (int mi = 0; mi < 4; ++mi) {
            int krow = mi * 16 + lc;
            bf16x8 a0 = *(const bf16x8*)&Ks[krow * 64 + ((lg * 8) ^ swl)];
            bf16x8 a1 = *(const bf16x8*)&Ks[krow * 64 + ((32 + lg * 8) ^ swl)];
            f32x4 s = (f32x4){0.f, 0.f, 0.f, 0.f};
            s = mfma16(a0, bq0, s);
            s = mfma16(a1, bq1, s);
            sacc[mi] = s;
        }

        // aw * mask * exp -> P (bf16, packed b64 writes), psum accumulate
        #pragma unroll
        for (int mi = 0; mi < 4; ++mi) {
            int kb = k0 + mi * 16 + lg * 4;
            float4 awv = *(const float4*)&awrow[kb];
            float pv[4];
            unsigned mk[4];
            if (mode == 0) {
                int4 mv = *(const int4*)&((const int*)maskp)[mrowo + kb];
                mk[0] = mv.x != 0; mk[1] = mv.y != 0; mk[2] = mv.z != 0; mk[3] = mv.w != 0;
            } else if (mode == 1) {
                unsigned mu = *(const unsigned*)&((const unsigned char*)maskp)[mrowo + kb];
                mk[0] = mu & 0xffu; mk[1] = (mu >> 8) & 0xffu;
                mk[2] = (mu >> 16) & 0xffu; mk[3] = (mu >> 24) & 0xffu;
            } else {
                float4 mv = *(const float4*)&((const float*)maskp)[mrowo + kb];
                mk[0] = mv.x != 0.f; mk[1] = mv.y != 0.f; mk[2] = mv.z != 0.f; mk[3] = mv.w != 0.f;
            }
            const float aww[4] = {awv.x, awv.y, awv.z, awv.w};
            #pragma unroll
            for (int r = 0; r < 4; ++r) {
                float sv = sacc[mi][r] * aww[r];
                pv[r] = mk[r] ? 0.f : __expf(sv);
                psum += pv[r];
            }
            uint2 pk;
            pk.x = (unsigned)f2bfu(pv[0]) | ((unsigned)f2bfu(pv[1]) << 16);
            pk.y = (unsigned)f2bfu(pv[2]) | ((unsigned)f2bfu(pv[3]) << 16);
            *(uint2*)&Ps[(wq + lc) * 64 + ((mi * 16 + lg * 4) ^ swl)] = pk;
        }

        // PV: out[q][d] += P[q][k] * V[k][d]  (Vt rows = d)
        #pragma unroll
        for (int kk = 0; kk < 2; ++kk) {
            bf16x8 pa = *(const bf16x8*)&Ps[(wq + lc) * 64 + ((kk * 32 + lg * 8) ^ swl)];
            #pragma unroll
            for (int nj = 0; nj < 4; ++nj) {
                bf16x8 vb = *(const bf16x8*)&Vs[(nj * 16 + lc) * 64 + ((kk * 32 + lg * 8) ^ swl)];
                oacc[nj] = mfma16(pa, vb, oacc[nj]);
            }
        }
        __syncthreads();   // K/V reads done
        if (t < 15) {
            int kn = k0 + 64;
            #pragma unroll
            for (int ci = 0; ci < 2; ++ci) {
                int c = w + ci * 4;
                gll16(&kp[(size_t)(b * NN + kn + c * 8 + srow) * DM + h * 64 + scol], &Ks[c * 512]);
                gll16(&vt[(size_t)(bh * 64 + c * 8 + srow) * NN + kn + scol], &Vs[c * 512]);
            }
        }
    }

    // full row-sums: lane's psum covers k = {16m + 4*lg + r}; reduce over lg
    psum += __shfl_xor(psum, 16);
    psum += __shfl_xor(psum, 32);
    float inv = 1.0f / psum;                 // for q = wq+lc
    float invr[4];
    #pragma unroll
    for (int r = 0; r < 4; ++r)
        invr[r] = __shfl(inv, (lane & 48) | (lg * 4 + r));   // q' = wq+lg*4+r

    #pragma unroll
    for (int nj = 0; nj < 4; ++nj)
        #pragma unroll
        for (int r = 0; r < 4; ++r) {
            int qq = q0 + wq + lg * 4 + r;
            float v = oacc[nj][r] * invr[r];
            ob[(size_t)(b * NN + qq) * DM + h * 64 + nj * 16 + lc] = f2bfu(v);
        }
}

// ---------------------------------------------------------------------------
extern "C" void kernel_launch(void* const* d_in, const int* in_sizes, int n_in,
                              void* d_out, int out_size, void* d_ws, size_t ws_size,
                              hipStream_t stream) {
    const float* xin_f[3] = {(const float*)d_in[0], (const float*)d_in[1], (const float*)d_in[2]};
    const void*  maskp   = d_in[3];
    const float* aw      = (const float*)d_in[4];
    const float* memv    = (const float*)d_in[5];
    const float* Wp_f[3] = {(const float*)d_in[6], (const float*)d_in[8], (const float*)d_in[10]};
    const float* bp[3]   = {(const float*)d_in[7], (const float*)d_in[9], (const float*)d_in[11]};
    const float* Wo_f  = (const float*)d_in[12];  const float* bo  = (const float*)d_in[13];
    const float* Wmm = (const float*)d_in[14];    const float* bmm = (const float*)d_in[15];
    const float* W1f[3] = {(const float*)d_in[16], (const float*)d_in[20], (const float*)d_in[24]};
    const float* b1a[3] = {(const float*)d_in[17], (const float*)d_in[21], (const float*)d_in[25]};
    const float* W2f[3] = {(const float*)d_in[18], (const float*)d_in[22], (const float*)d_in[26]};
    const float* b2a[3] = {(const float*)d_in[19], (const float*)d_in[23], (const float*)d_in[27]};

    char* p = (char*)d_ws;
    auto alloc = [&](size_t bytes) { char* r = p; p += (bytes + 255) & ~(size_t)255; return r; };
    int*    mflags = (int*)alloc(256);
    ushort* xbf  = (ushort*)alloc((size_t)TT * DM * 2);
    ushort* Wpb[3]; for (int t = 0; t < 3; ++t) Wpb[t] = (ushort*)alloc((size_t)DM * DM * 2);
    ushort* Wob  = (ushort*)alloc((size_t)DM * DM * 2);
    ushort* W1b[3]; for (int t = 0; t < 3; ++t) W1b[t] = (ushort*)alloc((size_t)HID * DM * 2);
    ushort* W2b[3]; for (int t = 0; t < 3; ++t) W2b[t] = (ushort*)alloc((size_t)DM * HID * 2);
    ushort* hbuf = (ushort*)alloc((size_t)TT * HID * 2);
    ushort* xg   = (ushort*)alloc((size_t)TT * DM * 2);
    ushort* qpb  = (ushort*)alloc((size_t)TT * DM * 2);
    ushort* ksb  = (ushort*)alloc((size_t)TT * DM * 2);
    ushort* vtb  = (ushort*)alloc((size_t)TT * DM * 2);
    ushort* obuf = (ushort*)alloc((size_t)TT * DM * 2);

    hipMemsetAsync(mflags, 0, 8, stream);
    detect_mask_kernel<<<512, 256, 0, stream>>>((const unsigned char*)maskp,
                                                BB * NN * NN, mflags);

    // weight converts (f32 -> bf16)
    for (int t = 0; t < 3; ++t) {
        cvt_bf16<<<1024, 256, 0, stream>>>(Wp_f[t], Wpb[t], DM * DM / 4);
        cvt_bf16<<<512, 256, 0, stream>>>(W1f[t], W1b[t], HID * DM / 4);
        cvt_bf16<<<512, 256, 0, stream>>>(W2f[t], W2b[t], DM * HID / 4);
    }
    cvt_bf16<<<1024, 256, 0, stream>>>(Wo_f, Wob, DM * DM / 4);

    const dim3 blk(256);
    const dim3 g_fc1(TT / 128, HID / 128);   // (32, 4)
    const dim3 g_big(TT / 128, DM / 128);    // (32, 8)

    for (int t = 0; t < 3; ++t) {
        cvt_bf16<<<2048, 256, 0, stream>>>(xin_f[t], xbf, TT * DM / 4);
        gemm_bf16<1><<<g_fc1, blk, 0, stream>>>(xbf, W1b[t], b1a[t], hbuf,
            TT, HID, DM, 1.f, nullptr, nullptr, nullptr, nullptr);
        gemm_bf16<2><<<g_big, blk, 0, stream>>>(hbuf, W2b[t], b2a[t], xg,
            TT, DM, HID, 1.f, xin_f[t], nullptr, nullptr, nullptr);
        if (t == 0)
            gemm_bf16<0><<<g_big, blk, 0, stream>>>(xg, Wpb[t], bp[t], qpb,
                TT, DM, DM, 0.125f, nullptr, nullptr, nullptr, nullptr);
        else if (t == 1)
            gemm_bf16<3><<<g_big, blk, 0, stream>>>(xg, Wpb[t], bp[t], ksb,
                TT, DM, DM, 1.f, nullptr, memv, Wmm, bmm);
        else
            gemm_bf16<5><<<g_big, blk, 0, stream>>>(xg, Wpb[t], bp[t], vtb,
                TT, DM, DM, 1.f, nullptr, memv, Wmm, bmm);
    }

    attn_mfma<<<dim3(NN / 64, BB * HH), blk, 0, stream>>>(qpb, ksb, vtb, aw,
                                                          maskp, mflags, obuf);

    gemm_bf16<4><<<g_big, blk, 0, stream>>>(obuf, Wob, bo, d_out,
        TT, DM, DM, 1.f, nullptr, nullptr, nullptr, nullptr);
}

// Round 3
// 302.719 us; speedup vs baseline: 4.5065x; 1.2862x over previous
//
#include <hip/hip_runtime.h>
#include <hip/hip_bf16.h>

#define BB    4
#define NN    1024
#define DM    1024
#define HH    16
#define HID   512
#define TT    (BB * NN)

typedef __attribute__((ext_vector_type(8))) short bf16x8;
typedef __attribute__((ext_vector_type(4))) float f32x4;

__device__ __forceinline__ ushort f2bfu(float f) {
    __hip_bfloat16 h = __float2bfloat16(f);
    return __builtin_bit_cast(ushort, h);
}

__device__ __forceinline__ f32x4 mfma16(bf16x8 a, bf16x8 b, f32x4 c) {
    return __builtin_amdgcn_mfma_f32_16x16x32_bf16(a, b, c, 0, 0, 0);
}

// async 16B/lane global->LDS; lds dest = wave-uniform base + lane*16
__device__ __forceinline__ void gll16(const void* g, void* l) {
    __builtin_amdgcn_global_load_lds(
        (const __attribute__((address_space(1))) unsigned int*)g,
        (__attribute__((address_space(3))) unsigned int*)l, 16, 0, 0);
}

// ---------------------------------------------------------------------------
__global__ void detect_mask_kernel(const unsigned char* __restrict__ m,
                                   int nbytes, int* __restrict__ flags) {
    int stride = blockDim.x * gridDim.x;
    int hi = 0, lo = 0;
    for (int i = blockIdx.x * blockDim.x + threadIdx.x; i < nbytes; i += stride) {
        unsigned char v = m[i];
        if (v) { if (i & 3) hi = 1; else lo = 1; }
    }
    if (hi) atomicOr(&flags[0], 1);
    if (lo) atomicOr(&flags[1], 1);
}

// ---------------------------------------------------------------------------
// Batched f32->bf16 convert: NS equal-size segments (n4 float4s each).
// Segment/pointer select via cndmask chain (compile-time indices only).
// ---------------------------------------------------------------------------
template <int NS>
struct CvtArgs { const float* s[NS]; ushort* d[NS]; };

template <int NS>
__global__ __launch_bounds__(256) void cvt_multi(CvtArgs<NS> a, int n4) {
    int total = n4 * NS;
    int stride = blockDim.x * gridDim.x;
    for (int i = blockIdx.x * blockDim.x + threadIdx.x; i < total; i += stride) {
        const float* sp = a.s[0];
        ushort* dp = a.d[0];
        #pragma unroll
        for (int k = 1; k < NS; ++k) {
            bool ge = i >= k * n4;
            sp = ge ? a.s[k] : sp;
            dp = ge ? a.d[k] : dp;
        }
        int j = i % n4;
        float4 v = ((const float4*)sp)[j];
        uint2 o;
        o.x = (unsigned)f2bfu(v.x) | ((unsigned)f2bfu(v.y) << 16);
        o.y = (unsigned)f2bfu(v.z) | ((unsigned)f2bfu(v.w) << 16);
        ((uint2*)dp)[j] = o;
    }
}

// ---------------------------------------------------------------------------
// Batched bf16 MFMA GEMM over blockIdx.z: C[m][e] = epi( A[m][:]·W[e][:] + b[e] )
// BM=BN=128, BK=64, 256 thr (4 waves, 64x64 each = 4x4 frags of 16x16x32).
// LDS [128 rows][64 bf16], 16B-slot XOR swizzle (row&7) applied on the
// pre-swizzled global source (global_load_lds writes linearly).
// EP: 1 relu->bf16 | 2 X*sigmoid->bf16 | 4 bias->f32 |
//     7 per-z proj: z0 bias*0.125->bf16, z1 (.)*(mem*Wmm+bmm)->bf16,
//                   z2 same + transposed store vt[b][h][d][n]
// ---------------------------------------------------------------------------
struct GB {
    const ushort* A[3]; const ushort* W[3];
    const float* bias[3]; void* C[3]; const float* X[3];
};

template <int EP>
__global__ __launch_bounds__(256) void gemm_bf16(
    GB gb, int M, int N, int K,
    const float* __restrict__ mem, const float* __restrict__ Wmm,
    const float* __restrict__ bmm)
{
    __shared__ __align__(16) ushort As[128 * 64];
    __shared__ __align__(16) ushort Bs[128 * 64];
    const int z = blockIdx.z;
    const ushort* A = gb.A[z];
    const ushort* W = gb.W[z];
    const float* bias = gb.bias[z];
    void* Cout = gb.C[z];
    const float* X = gb.X[z];

    const int tid = threadIdx.x;
    const int lane = tid & 63, w = tid >> 6;
    const int lc = lane & 15, lg = lane >> 4;
    const int m0 = blockIdx.x * 128, n0 = blockIdx.y * 128;
    const int wm = (w >> 1) * 64, wn = (w & 1) * 64;
    const int srow = lane >> 3, scol = 8 * ((lane & 7) ^ srow);
    const int swl = (lc & 7) << 3;

    f32x4 acc[4][4];
    #pragma unroll
    for (int i = 0; i < 4; ++i)
        #pragma unroll
        for (int j = 0; j < 4; ++j)
            acc[i][j] = (f32x4){0.f, 0.f, 0.f, 0.f};

    #pragma unroll
    for (int ci = 0; ci < 4; ++ci) {
        int c = w + ci * 4;
        gll16(&A[(size_t)(m0 + c * 8 + srow) * K + 0 + scol], &As[c * 512]);
        gll16(&W[(size_t)(n0 + c * 8 + srow) * K + 0 + scol], &Bs[c * 512]);
    }

    for (int k0 = 0; k0 < K; k0 += 64) {
        __syncthreads();
        bf16x8 af[4][2], bfr[4][2];
        #pragma unroll
        for (int mi = 0; mi < 4; ++mi) {
            int row = wm + mi * 16 + lc;
            af[mi][0] = *(const bf16x8*)&As[row * 64 + ((lg * 8) ^ swl)];
            af[mi][1] = *(const bf16x8*)&As[row * 64 + ((32 + lg * 8) ^ swl)];
        }
        #pragma unroll
        for (int nj = 0; nj < 4; ++nj) {
            int row = wn + nj * 16 + lc;
            bfr[nj][0] = *(const bf16x8*)&Bs[row * 64 + ((lg * 8) ^ swl)];
            bfr[nj][1] = *(const bf16x8*)&Bs[row * 64 + ((32 + lg * 8) ^ swl)];
        }
        #pragma unroll
        for (int mi = 0; mi < 4; ++mi)
            #pragma unroll
            for (int nj = 0; nj < 4; ++nj) {
                acc[mi][nj] = mfma16(af[mi][0], bfr[nj][0], acc[mi][nj]);
                acc[mi][nj] = mfma16(af[mi][1], bfr[nj][1], acc[mi][nj]);
            }
        __syncthreads();
        if (k0 + 64 < K) {
            int kn = k0 + 64;
            #pragma unroll
            for (int ci = 0; ci < 4; ++ci) {
                int c = w + ci * 4;
                gll16(&A[(size_t)(m0 + c * 8 + srow) * K + kn + scol], &As[c * 512]);
                gll16(&W[(size_t)(n0 + c * 8 + srow) * K + kn + scol], &Bs[c * 512]);
            }
        }
    }

    // epilogue: C row = m0+wm+mi*16+lg*4+r, col = n0+wn+nj*16+lc
    #pragma unroll
    for (int nj = 0; nj < 4; ++nj) {
        int e = n0 + wn + nj * 16 + lc;
        float bv = bias[e];
        float wmv = 0.f, bmv = 0.f;
        if (EP == 7) { wmv = Wmm[e]; bmv = bmm[e]; }
        #pragma unroll
        for (int mi = 0; mi < 4; ++mi) {
            int mbase = m0 + wm + mi * 16 + lg * 4;
            if (EP == 7 && z == 2) {
                // V-proj: transposed store vt[b][h][d][n]
                ushort u[4];
                #pragma unroll
                for (int r = 0; r < 4; ++r) {
                    float v = (acc[mi][nj][r] + bv) * (mem[mbase + r] * wmv + bmv);
                    u[r] = f2bfu(v);
                }
                int bb = mbase >> 10, n = mbase & 1023;
                size_t off = ((size_t)(bb * HH + (e >> 6)) * 64 + (e & 63)) * NN + n;
                uint2 pk;
                pk.x = (unsigned)u[0] | ((unsigned)u[1] << 16);
                pk.y = (unsigned)u[2] | ((unsigned)u[3] << 16);
                *(uint2*)&((ushort*)Cout)[off] = pk;
            } else {
                #pragma unroll
                for (int r = 0; r < 4; ++r) {
                    int m = mbase + r;
                    float v = acc[mi][nj][r] + bv;
                    if (EP == 1) v = fmaxf(v, 0.f);
                    if (EP == 2) v = X[(size_t)m * N + e] * (1.f / (1.f + __expf(-v)));
                    if (EP == 7) {
                        if (z == 0) v = v * 0.125f;
                        else        v = v * (mem[m] * wmv + bmv);
                    }
                    size_t off = (size_t)m * N + e;
                    if (EP == 4) ((float*)Cout)[off] = v;
                    else         ((ushort*)Cout)[off] = f2bfu(v);
                }
            }
        }
    }
}

// ---------------------------------------------------------------------------
// MFMA flash attention (unchanged from R2). Block = (b,h, 64 q-rows), 4 waves.
// S^T = K·Q^T so lane holds 4 consecutive k for one q -> float4 aw/mask loads.
// Max-free softmax; PV via Vt rows (d-major); out /= rowsum(P).
// ---------------------------------------------------------------------------
__global__ __launch_bounds__(256) void attn_mfma(
    const ushort* __restrict__ qp, const ushort* __restrict__ kp,
    const ushort* __restrict__ vt, const float* __restrict__ aw,
    const void* __restrict__ maskp, const int* __restrict__ mflags,
    ushort* __restrict__ ob)
{
    __shared__ __align__(16) ushort Qs[64 * 64];
    __shared__ __align__(16) ushort Ks[64 * 64];
    __shared__ __align__(16) ushort Vs[64 * 64];
    __shared__ __align__(16) ushort Ps[64 * 64];
    const int tid = threadIdx.x, lane = tid & 63, w = tid >> 6;
    const int lc = lane & 15, lg = lane >> 4;
    const int qt = blockIdx.x, bh = blockIdx.y;
    const int b = bh >> 4, h = bh & 15;
    const int q0 = qt * 64, wq = w * 16;
    const int mode = mflags[0] ? (mflags[1] ? 1 : 2) : 0;
    const int srow = lane >> 3, scol = 8 * ((lane & 7) ^ srow);
    const int swl = (lc & 7) << 3;

    #pragma unroll
    for (int ci = 0; ci < 2; ++ci) {
        int c = w + ci * 4;
        gll16(&qp[(size_t)(b * NN + q0 + c * 8 + srow) * DM + h * 64 + scol], &Qs[c * 512]);
        gll16(&kp[(size_t)(b * NN + 0 + c * 8 + srow) * DM + h * 64 + scol], &Ks[c * 512]);
        gll16(&vt[(size_t)(bh * 64 + c * 8 + srow) * NN + 0 + scol], &Vs[c * 512]);
    }

    f32x4 oacc[4];
    #pragma unroll
    for (int i = 0; i < 4; ++i) oacc[i] = (f32x4){0.f, 0.f, 0.f, 0.f};
    float psum = 0.f;
    const int q = q0 + wq + lc;
    const float* awrow = aw + ((size_t)(bh) * NN + q) * NN;
    const size_t mrowo = ((size_t)b * NN + q) * NN;

    for (int t = 0; t < 16; ++t) {
        const int k0 = t * 64;
        __syncthreads();

        bf16x8 bq0 = *(const bf16x8*)&Qs[(wq + lc) * 64 + ((lg * 8) ^ swl)];
        bf16x8 bq1 = *(const bf16x8*)&Qs[(wq + lc) * 64 + ((32 + lg * 8) ^ swl)];
        f32x4 sacc[4];
        #pragma unroll
        for (int mi = 0; mi < 4; ++mi) {
            int krow = mi * 16 + lc;
            bf16x8 a0 = *(const bf16x8*)&Ks[krow * 64 + ((lg * 8) ^ swl)];
            bf16x8 a1 = *(const bf16x8*)&Ks[krow * 64 + ((32 + lg * 8) ^ swl)];
            f32x4 s = (f32x4){0.f, 0.f, 0.f, 0.f};
            s = mfma16(a0, bq0, s);
            s = mfma16(a1, bq1, s);
            sacc[mi] = s;
        }

        #pragma unroll
        for (int mi = 0; mi < 4; ++mi) {
            int kb = k0 + mi * 16 + lg * 4;
            float4 awv = *(const float4*)&awrow[kb];
            float pv[4];
            unsigned mk[4];
            if (mode == 0) {
                int4 mv = *(const int4*)&((const int*)maskp)[mrowo + kb];
                mk[0] = mv.x != 0; mk[1] = mv.y != 0; mk[2] = mv.z != 0; mk[3] = mv.w != 0;
            } else if (mode == 1) {
                unsigned mu = *(const unsigned*)&((const unsigned char*)maskp)[mrowo + kb];
                mk[0] = mu & 0xffu; mk[1] = (mu >> 8) & 0xffu;
                mk[2] = (mu >> 16) & 0xffu; mk[3] = (mu >> 24) & 0xffu;
            } else {
                float4 mv = *(const float4*)&((const float*)maskp)[mrowo + kb];
                mk[0] = mv.x != 0.f; mk[1] = mv.y != 0.f; mk[2] = mv.z != 0.f; mk[3] = mv.w != 0.f;
            }
            const float aww[4] = {awv.x, awv.y, awv.z, awv.w};
            #pragma unroll
            for (int r = 0; r < 4; ++r) {
                float sv = sacc[mi][r] * aww[r];
                pv[r] = mk[r] ? 0.f : __expf(sv);
                psum += pv[r];
            }
            uint2 pk;
            pk.x = (unsigned)f2bfu(pv[0]) | ((unsigned)f2bfu(pv[1]) << 16);
            pk.y = (unsigned)f2bfu(pv[2]) | ((unsigned)f2bfu(pv[3]) << 16);
            *(uint2*)&Ps[(wq + lc) * 64 + ((mi * 16 + lg * 4) ^ swl)] = pk;
        }

        #pragma unroll
        for (int kk = 0; kk < 2; ++kk) {
            bf16x8 pa = *(const bf16x8*)&Ps[(wq + lc) * 64 + ((kk * 32 + lg * 8) ^ swl)];
            #pragma unroll
            for (int nj = 0; nj < 4; ++nj) {
                bf16x8 vb = *(const bf16x8*)&Vs[(nj * 16 + lc) * 64 + ((kk * 32 + lg * 8) ^ swl)];
                oacc[nj] = mfma16(pa, vb, oacc[nj]);
            }
        }
        __syncthreads();
        if (t < 15) {
            int kn = k0 + 64;
            #pragma unroll
            for (int ci = 0; ci < 2; ++ci) {
                int c = w + ci * 4;
                gll16(&kp[(size_t)(b * NN + kn + c * 8 + srow) * DM + h * 64 + scol], &Ks[c * 512]);
                gll16(&vt[(size_t)(bh * 64 + c * 8 + srow) * NN + kn + scol], &Vs[c * 512]);
            }
        }
    }

    psum += __shfl_xor(psum, 16);
    psum += __shfl_xor(psum, 32);
    float inv = 1.0f / psum;
    float invr[4];
    #pragma unroll
    for (int r = 0; r < 4; ++r)
        invr[r] = __shfl(inv, (lane & 48) | (lg * 4 + r));

    #pragma unroll
    for (int nj = 0; nj < 4; ++nj)
        #pragma unroll
        for (int r = 0; r < 4; ++r) {
            int qq = q0 + wq + lg * 4 + r;
            float v = oacc[nj][r] * invr[r];
            ob[(size_t)(b * NN + qq) * DM + h * 64 + nj * 16 + lc] = f2bfu(v);
        }
}

// ---------------------------------------------------------------------------
extern "C" void kernel_launch(void* const* d_in, const int* in_sizes, int n_in,
                              void* d_out, int out_size, void* d_ws, size_t ws_size,
                              hipStream_t stream) {
    const float* xin_f[3] = {(const float*)d_in[0], (const float*)d_in[1], (const float*)d_in[2]};
    const void*  maskp   = d_in[3];
    const float* aw      = (const float*)d_in[4];
    const float* memv    = (const float*)d_in[5];
    const float* Wp_f[3] = {(const float*)d_in[6], (const float*)d_in[8], (const float*)d_in[10]};
    const float* bp[3]   = {(const float*)d_in[7], (const float*)d_in[9], (const float*)d_in[11]};
    const float* Wo_f  = (const float*)d_in[12];  const float* bo  = (const float*)d_in[13];
    const float* Wmm = (const float*)d_in[14];    const float* bmm = (const float*)d_in[15];
    const float* W1f[3] = {(const float*)d_in[16], (const float*)d_in[20], (const float*)d_in[24]};
    const float* b1a[3] = {(const float*)d_in[17], (const float*)d_in[21], (const float*)d_in[25]};
    const float* W2f[3] = {(const float*)d_in[18], (const float*)d_in[22], (const float*)d_in[26]};
    const float* b2a[3] = {(const float*)d_in[19], (const float*)d_in[23], (const float*)d_in[27]};

    char* p = (char*)d_ws;
    auto alloc = [&](size_t bytes) { char* r = p; p += (bytes + 255) & ~(size_t)255; return r; };
    int*    mflags = (int*)alloc(256);
    ushort* xbf[3]; for (int t = 0; t < 3; ++t) xbf[t] = (ushort*)alloc((size_t)TT * DM * 2);
    ushort* Wpb[3]; for (int t = 0; t < 3; ++t) Wpb[t] = (ushort*)alloc((size_t)DM * DM * 2);
    ushort* Wob  = (ushort*)alloc((size_t)DM * DM * 2);
    ushort* W1b[3]; for (int t = 0; t < 3; ++t) W1b[t] = (ushort*)alloc((size_t)HID * DM * 2);
    ushort* W2b[3]; for (int t = 0; t < 3; ++t) W2b[t] = (ushort*)alloc((size_t)DM * HID * 2);
    ushort* hbuf[3]; for (int t = 0; t < 3; ++t) hbuf[t] = (ushort*)alloc((size_t)TT * HID * 2);
    ushort* xg[3];  for (int t = 0; t < 3; ++t) xg[t] = (ushort*)alloc((size_t)TT * DM * 2);
    ushort* qpb  = (ushort*)alloc((size_t)TT * DM * 2);
    ushort* ksb  = (ushort*)alloc((size_t)TT * DM * 2);
    ushort* vtb  = (ushort*)alloc((size_t)TT * DM * 2);
    ushort* obuf = (ushort*)alloc((size_t)TT * DM * 2);

    hipMemsetAsync(mflags, 0, 8, stream);
    detect_mask_kernel<<<512, 256, 0, stream>>>((const unsigned char*)maskp,
                                                BB * NN * NN, mflags);

    // f32 -> bf16 conversions: 3 dispatches, equal-size segments each
    {
        CvtArgs<3> a;   // inputs: 4M elements each
        for (int t = 0; t < 3; ++t) { a.s[t] = xin_f[t]; a.d[t] = xbf[t]; }
        cvt_multi<3><<<2048, 256, 0, stream>>>(a, TT * DM / 4);
    }
    {
        CvtArgs<4> a;   // 1M-element weights
        a.s[0] = Wp_f[0]; a.d[0] = Wpb[0];
        a.s[1] = Wp_f[1]; a.d[1] = Wpb[1];
        a.s[2] = Wp_f[2]; a.d[2] = Wpb[2];
        a.s[3] = Wo_f;    a.d[3] = Wob;
        cvt_multi<4><<<2048, 256, 0, stream>>>(a, DM * DM / 4);
    }
    {
        CvtArgs<6> a;   // 512K-element weights
        for (int t = 0; t < 3; ++t) { a.s[t] = W1f[t]; a.d[t] = W1b[t]; }
        for (int t = 0; t < 3; ++t) { a.s[3 + t] = W2f[t]; a.d[3 + t] = W2b[t]; }
        cvt_multi<6><<<2048, 256, 0, stream>>>(a, HID * DM / 4);
    }

    const dim3 blk(256);
    GB g1 = {}, g2 = {}, g3 = {}, g4 = {};
    for (int t = 0; t < 3; ++t) {
        g1.A[t] = xbf[t];  g1.W[t] = W1b[t]; g1.bias[t] = b1a[t]; g1.C[t] = hbuf[t];
        g2.A[t] = hbuf[t]; g2.W[t] = W2b[t]; g2.bias[t] = b2a[t]; g2.C[t] = xg[t]; g2.X[t] = xin_f[t];
        g3.A[t] = xg[t];   g3.W[t] = Wpb[t]; g3.bias[t] = bp[t];
    }
    g3.C[0] = qpb; g3.C[1] = ksb; g3.C[2] = vtb;
    g4.A[0] = obuf; g4.W[0] = Wob; g4.bias[0] = bo; g4.C[0] = d_out;

    gemm_bf16<1><<<dim3(TT / 128, HID / 128, 3), blk, 0, stream>>>(g1, TT, HID, DM, nullptr, nullptr, nullptr);
    gemm_bf16<2><<<dim3(TT / 128, DM / 128, 3), blk, 0, stream>>>(g2, TT, DM, HID, nullptr, nullptr, nullptr);
    gemm_bf16<7><<<dim3(TT / 128, DM / 128, 3), blk, 0, stream>>>(g3, TT, DM, DM, memv, Wmm, bmm);

    attn_mfma<<<dim3(NN / 64, BB * HH), blk, 0, stream>>>(qpb, ksb, vtb, aw,
                                                          maskp, mflags, obuf);

    gemm_bf16<4><<<dim3(TT / 128, DM / 128, 1), blk, 0, stream>>>(g4, TT, DM, DM, nullptr, nullptr, nullptr);
}